// Round 3
// baseline (93.504 us; speedup 1.0000x reference)
//
#include <hip/hip_runtime.h>

// Coulomb pair-energy reduction via 2D pair bucketing + LDS-staged atom tiles.
// inputs: 0 coords f32[100000*3], 1 pairs i32[6400000*2], 2 box f32[9],
//         3 charges f32[100000], 4 prefac f32[1], 5 cutoff f32[1], 6 do_shift i32[1]
// output: f32[1] = prefac * sum_masked(q_i q_j (1/r - shift))
//
// R2 theory: R0/R1 are MSHR-limited on 12.8M random 16B L2 gathers (~3.2 cyc
// per miss per CU, residency-insensitive). Fix = gather from LDS: bucket pairs
// by (i>>12, j>>12), stage the two 64KB atom chunks per bucket in LDS.

constexpr int TPB = 256;

constexpr int CHUNK_SHIFT = 12;
constexpr int CHUNK       = 1 << CHUNK_SHIFT;   // 4096 atoms per chunk
constexpr int NCHUNK_MAX  = 32;                 // natoms <= 131072
constexpr int NBUCKET_MAX = NCHUNK_MAX * NCHUNK_MAX;
constexpr int CAP         = 13312;              // slots per bucket (mean ~10740 + 24 sigma)
constexpr int OV_CAP      = 262144;             // overflow pairs (safety net)

// ws layout (bytes)
constexpr size_t WS_ACC    = 0;        // double
constexpr size_t WS_PAR    = 16;       // float[20]
constexpr size_t WS_GCOUNT = 128;      // u32[NBUCKET_MAX] (4KB)
constexpr size_t WS_OVCNT  = 4224;     // u32
constexpr size_t WS_OVLIST = 4352;     // int2[OV_CAP] (2MB)
constexpr size_t WS_ATOMS  = 4u << 20; // float4[natoms]
constexpr size_t WS_BUCKET = 8u << 20; // u32[nbucket*CAP]
constexpr size_t WS_ZERO_LEN = WS_OVCNT + 128;  // memset range covers acc..ovcnt

__global__ void setup_kernel(const float* __restrict__ box,
                             const float* __restrict__ cutoff_p,
                             const int* __restrict__ do_shift_p,
                             double* __restrict__ acc,
                             float* __restrict__ par) {
    if (threadIdx.x == 0 && blockIdx.x == 0) {
        *acc = 0.0;
        float b00 = box[0], b01 = box[1], b02 = box[2];
        float b10 = box[3], b11 = box[4], b12 = box[5];
        float b20 = box[6], b21 = box[7], b22 = box[8];
        float det = b00*(b11*b22 - b12*b21)
                  - b01*(b10*b22 - b12*b20)
                  + b02*(b10*b21 - b11*b20);
        float id = 1.0f / det;
        par[0] =  (b11*b22 - b12*b21) * id;
        par[1] = -(b01*b22 - b02*b21) * id;
        par[2] =  (b01*b12 - b02*b11) * id;
        par[3] = -(b10*b22 - b12*b20) * id;
        par[4] =  (b00*b22 - b02*b20) * id;
        par[5] = -(b00*b12 - b02*b10) * id;
        par[6] =  (b10*b21 - b11*b20) * id;
        par[7] = -(b00*b21 - b01*b20) * id;
        par[8] =  (b00*b11 - b01*b10) * id;
        float cut = *cutoff_p;
        par[9]  = cut * cut;
        par[10] = (*do_shift_p) ? (1.0f / cut) : 0.0f;
        par[11] = b00; par[12] = b01; par[13] = b02;
        par[14] = b10; par[15] = b11; par[16] = b12;
        par[17] = b20; par[18] = b21; par[19] = b22;
    }
}

__global__ void pack_atoms_kernel(const float* __restrict__ coords,
                                  const float* __restrict__ charges,
                                  float4* __restrict__ atoms, int n) {
    int i = blockIdx.x * blockDim.x + threadIdx.x;
    if (i < n) {
        atoms[i] = make_float4(coords[3*i], coords[3*i + 1], coords[3*i + 2],
                               charges[i]);
    }
}

__device__ __forceinline__ float pair_e(float4 ai, float4 aj, const float* P) {
    float dx = ai.x - aj.x, dy = ai.y - aj.y, dz = ai.z - aj.z;
    float sx = dx*P[0] + dy*P[3] + dz*P[6];
    float sy = dx*P[1] + dy*P[4] + dz*P[7];
    float sz = dx*P[2] + dy*P[5] + dz*P[8];
    sx -= floorf(sx + 0.5f);
    sy -= floorf(sy + 0.5f);
    sz -= floorf(sz + 0.5f);
    float px = sx*P[11] + sy*P[14] + sz*P[17];
    float py = sx*P[12] + sy*P[15] + sz*P[18];
    float pz = sx*P[13] + sy*P[16] + sz*P[19];
    float r2 = px*px + py*py + pz*pz;
    float rinv = rsqrtf(r2);
    float e = ai.w * aj.w * (rinv - P[10]);
    return (r2 <= P[9]) ? e : 0.0f;
}

// ---------------- bucket path ----------------

constexpr int S_TPB = 512;
constexpr int S_PPT = 32;                 // pairs per thread (in registers)
constexpr int S_PPB = S_TPB * S_PPT;      // 16384 pairs per block

__global__ __launch_bounds__(S_TPB)
void scatter_kernel(const int2* __restrict__ pairs, int npairs,
                    int nchunk, int nbucket,
                    unsigned* __restrict__ gcount,
                    unsigned* __restrict__ ovcount, int2* __restrict__ ovlist,
                    unsigned* __restrict__ bucket_data) {
    __shared__ unsigned hist[NBUCKET_MAX];
    for (int b = threadIdx.x; b < nbucket; b += S_TPB) hist[b] = 0u;
    __syncthreads();

    int base = blockIdx.x * S_PPB;
    int2 pr[S_PPT];
#pragma unroll
    for (int u = 0; u < S_PPT; ++u) {
        int p = base + u * S_TPB + threadIdx.x;
        pr[u] = (p < npairs) ? pairs[p] : make_int2(-1, -1);
    }
#pragma unroll
    for (int u = 0; u < S_PPT; ++u) {
        if (pr[u].x >= 0) {
            int b = (pr[u].x >> CHUNK_SHIFT) * nchunk + (pr[u].y >> CHUNK_SHIFT);
            atomicAdd(&hist[b], 1u);
        }
    }
    __syncthreads();
    // reserve global ranges; hist[b] becomes the running absolute cursor
    for (int b = threadIdx.x; b < nbucket; b += S_TPB) {
        unsigned c = hist[b];
        hist[b] = c ? atomicAdd(&gcount[b], c) : 0u;
    }
    __syncthreads();
#pragma unroll
    for (int u = 0; u < S_PPT; ++u) {
        if (pr[u].x >= 0) {
            int b = (pr[u].x >> CHUNK_SHIFT) * nchunk + (pr[u].y >> CHUNK_SHIFT);
            unsigned slot = atomicAdd(&hist[b], 1u);
            if (slot < (unsigned)CAP) {
                bucket_data[(size_t)b * CAP + slot] =
                    ((unsigned)(pr[u].x & (CHUNK - 1)) << 16) |
                     (unsigned)(pr[u].y & (CHUNK - 1));
            } else {
                unsigned o = atomicAdd(ovcount, 1u);
                if (o < (unsigned)OV_CAP) ovlist[o] = pr[u];
            }
        }
    }
}

constexpr int C_TPB = 1024;

__global__ __launch_bounds__(C_TPB)
void bucket_compute(const unsigned* __restrict__ bucket_data,
                    const unsigned* __restrict__ gcount,
                    const float4* __restrict__ atoms, int natoms, int nchunk,
                    const float* __restrict__ par, double* __restrict__ acc) {
    __shared__ float4 tA[CHUNK];
    __shared__ float4 tB[CHUNK];

    float P[20];
#pragma unroll
    for (int k = 0; k < 20; ++k) P[k] = par[k];

    int b  = blockIdx.x;
    int bx = b / nchunk, by = b - bx * nchunk;
    int gx = bx << CHUNK_SHIFT, gy = by << CHUNK_SHIFT;

    for (int t = threadIdx.x; t < CHUNK; t += C_TPB) {
        int ga = gx + t;
        tA[t] = (ga < natoms) ? atoms[ga] : make_float4(0.f, 0.f, 0.f, 0.f);
        int gb = gy + t;
        tB[t] = (gb < natoms) ? atoms[gb] : make_float4(0.f, 0.f, 0.f, 0.f);
    }
    __syncthreads();

    int n = min((int)gcount[b], CAP);
    const unsigned* bd = bucket_data + (size_t)b * CAP;
    double lsum = 0.0;
    int t = threadIdx.x;
    for (; t + 3 * C_TPB < n; t += 4 * C_TPB) {
        unsigned k0 = bd[t], k1 = bd[t + C_TPB], k2 = bd[t + 2*C_TPB], k3 = bd[t + 3*C_TPB];
        float4 a0 = tA[k0 >> 16], c0 = tB[k0 & 0xFFFFu];
        float4 a1 = tA[k1 >> 16], c1 = tB[k1 & 0xFFFFu];
        float4 a2 = tA[k2 >> 16], c2 = tB[k2 & 0xFFFFu];
        float4 a3 = tA[k3 >> 16], c3 = tB[k3 & 0xFFFFu];
        lsum += (double)pair_e(a0, c0, P) + (double)pair_e(a1, c1, P)
              + (double)pair_e(a2, c2, P) + (double)pair_e(a3, c3, P);
    }
    for (; t < n; t += C_TPB) {
        unsigned k = bd[t];
        lsum += (double)pair_e(tA[k >> 16], tB[k & 0xFFFFu], P);
    }

    // wave reduce
#pragma unroll
    for (int off = 32; off > 0; off >>= 1)
        lsum += __shfl_down(lsum, off);

    __syncthreads();  // tiles dead; reuse tA as the reduce scratch
    double* wsum = reinterpret_cast<double*>(tA);
    int lane = threadIdx.x & 63;
    int wid  = threadIdx.x >> 6;
    if (lane == 0) wsum[wid] = lsum;
    __syncthreads();
    if (threadIdx.x == 0) {
        double s = 0.0;
#pragma unroll
        for (int w = 0; w < C_TPB / 64; ++w) s += wsum[w];
        atomicAdd(acc, s);
    }
}

__global__ void overflow_kernel(const int2* __restrict__ ovlist,
                                const unsigned* __restrict__ ovcount_p,
                                const float4* __restrict__ atoms,
                                const float* __restrict__ par,
                                double* __restrict__ acc) {
    float P[20];
#pragma unroll
    for (int k = 0; k < 20; ++k) P[k] = par[k];
    int n = (int)min(*ovcount_p, (unsigned)OV_CAP);
    double lsum = 0.0;
    for (int t = blockIdx.x * blockDim.x + threadIdx.x; t < n;
         t += gridDim.x * blockDim.x) {
        int2 pr = ovlist[t];
        lsum += (double)pair_e(atoms[pr.x], atoms[pr.y], P);
    }
#pragma unroll
    for (int off = 32; off > 0; off >>= 1)
        lsum += __shfl_down(lsum, off);
    __shared__ double wsum[TPB / 64];
    int lane = threadIdx.x & 63;
    int wid  = threadIdx.x >> 6;
    if (lane == 0) wsum[wid] = lsum;
    __syncthreads();
    if (threadIdx.x == 0) {
        double s = 0.0;
#pragma unroll
        for (int w = 0; w < TPB / 64; ++w) s += wsum[w];
        if (s != 0.0) atomicAdd(acc, s);
    }
}

// ---------------- fallback path (R0 structure) ----------------

template<bool PACKED>
__global__ __launch_bounds__(TPB)
void coulomb_main(const int4* __restrict__ pairs4, int npairs4, int npairs,
                  const int2* __restrict__ pairs2,
                  const float4* __restrict__ atoms,
                  const float* __restrict__ coords,
                  const float* __restrict__ charges,
                  const float* __restrict__ par,
                  double* __restrict__ acc) {
    float P[20];
#pragma unroll
    for (int k = 0; k < 20; ++k) P[k] = par[k];

    double lsum = 0.0;
    int tid = blockIdx.x * blockDim.x + threadIdx.x;
    int stride = gridDim.x * blockDim.x;

    for (int p = tid; p < npairs4; p += stride) {
        int4 pr = pairs4[p];
        float4 a0, a1, b0, b1;
        if (PACKED) {
            a0 = atoms[pr.x]; a1 = atoms[pr.y];
            b0 = atoms[pr.z]; b1 = atoms[pr.w];
        } else {
            a0 = make_float4(coords[3*pr.x], coords[3*pr.x+1], coords[3*pr.x+2], charges[pr.x]);
            a1 = make_float4(coords[3*pr.y], coords[3*pr.y+1], coords[3*pr.y+2], charges[pr.y]);
            b0 = make_float4(coords[3*pr.z], coords[3*pr.z+1], coords[3*pr.z+2], charges[pr.z]);
            b1 = make_float4(coords[3*pr.w], coords[3*pr.w+1], coords[3*pr.w+2], charges[pr.w]);
        }
        lsum += (double)pair_e(a0, a1, P);
        lsum += (double)pair_e(b0, b1, P);
    }
    if (tid == 0 && (npairs & 1)) {
        int2 pr = pairs2[npairs - 1];
        float4 a0, a1;
        if (PACKED) { a0 = atoms[pr.x]; a1 = atoms[pr.y]; }
        else {
            a0 = make_float4(coords[3*pr.x], coords[3*pr.x+1], coords[3*pr.x+2], charges[pr.x]);
            a1 = make_float4(coords[3*pr.y], coords[3*pr.y+1], coords[3*pr.y+2], charges[pr.y]);
        }
        lsum += (double)pair_e(a0, a1, P);
    }
#pragma unroll
    for (int off = 32; off > 0; off >>= 1)
        lsum += __shfl_down(lsum, off);
    __shared__ double wsum[TPB / 64];
    int lane = threadIdx.x & 63;
    int wid  = threadIdx.x >> 6;
    if (lane == 0) wsum[wid] = lsum;
    __syncthreads();
    if (threadIdx.x == 0) {
        double s = 0.0;
#pragma unroll
        for (int w = 0; w < TPB / 64; ++w) s += wsum[w];
        atomicAdd(acc, s);
    }
}

__global__ void finalize_kernel(const double* __restrict__ acc,
                                const float* __restrict__ prefac_p,
                                float* __restrict__ out) {
    if (threadIdx.x == 0 && blockIdx.x == 0)
        out[0] = (float)(*acc * (double)(*prefac_p));
}

extern "C" void kernel_launch(void* const* d_in, const int* in_sizes, int n_in,
                              void* d_out, int out_size, void* d_ws, size_t ws_size,
                              hipStream_t stream) {
    const float* coords   = (const float*)d_in[0];
    const int*   pairs    = (const int*)d_in[1];
    const float* box      = (const float*)d_in[2];
    const float* charges  = (const float*)d_in[3];
    const float* prefac   = (const float*)d_in[4];
    const float* cutoff   = (const float*)d_in[5];
    const int*   do_shift = (const int*)d_in[6];
    float* out = (float*)d_out;

    int natoms = in_sizes[0] / 3;
    int npairs = in_sizes[1] / 2;

    double*   acc    = (double*)((char*)d_ws + WS_ACC);
    float*    par    = (float*)((char*)d_ws + WS_PAR);
    unsigned* gcount = (unsigned*)((char*)d_ws + WS_GCOUNT);
    unsigned* ovcnt  = (unsigned*)((char*)d_ws + WS_OVCNT);
    int2*     ovlist = (int2*)((char*)d_ws + WS_OVLIST);
    float4*   atoms  = (float4*)((char*)d_ws + WS_ATOMS);
    unsigned* bdata  = (unsigned*)((char*)d_ws + WS_BUCKET);

    int nchunk  = (natoms + CHUNK - 1) >> CHUNK_SHIFT;
    int nbucket = nchunk * nchunk;
    size_t need = WS_BUCKET + (size_t)nbucket * CAP * sizeof(unsigned);
    bool use_buckets = (nchunk <= NCHUNK_MAX) && (ws_size >= need);

    if (use_buckets) {
        hipMemsetAsync(d_ws, 0, WS_ZERO_LEN, stream);
        setup_kernel<<<1, 64, 0, stream>>>(box, cutoff, do_shift, acc, par);
        pack_atoms_kernel<<<(natoms + TPB - 1) / TPB, TPB, 0, stream>>>(
            coords, charges, atoms, natoms);

        int sblocks = (npairs + S_PPB - 1) / S_PPB;
        scatter_kernel<<<sblocks, S_TPB, 0, stream>>>(
            (const int2*)pairs, npairs, nchunk, nbucket,
            gcount, ovcnt, ovlist, bdata);

        bucket_compute<<<nbucket, C_TPB, 0, stream>>>(
            bdata, gcount, atoms, natoms, nchunk, par, acc);

        overflow_kernel<<<8, TPB, 0, stream>>>(ovlist, ovcnt, atoms, par, acc);
    } else {
        setup_kernel<<<1, 64, 0, stream>>>(box, cutoff, do_shift, acc, par);
        bool packed = (ws_size >= WS_ATOMS + (size_t)natoms * sizeof(float4));
        if (packed) {
            pack_atoms_kernel<<<(natoms + TPB - 1) / TPB, TPB, 0, stream>>>(
                coords, charges, atoms, natoms);
        }
        int npairs4 = npairs / 2;
        int blocks = (npairs4 + TPB - 1) / TPB;
        if (blocks > 2048) blocks = 2048;
        if (blocks < 1) blocks = 1;
        if (packed) {
            coulomb_main<true><<<blocks, TPB, 0, stream>>>(
                (const int4*)pairs, npairs4, npairs, (const int2*)pairs,
                atoms, coords, charges, par, acc);
        } else {
            coulomb_main<false><<<blocks, TPB, 0, stream>>>(
                (const int4*)pairs, npairs4, npairs, (const int2*)pairs,
                nullptr, coords, charges, par, acc);
        }
    }

    finalize_kernel<<<1, 64, 0, stream>>>(acc, prefac, out);
}